// Round 4
// baseline (877.694 us; speedup 1.0000x reference)
//
#include <hip/hip_runtime.h>

// ---------------------------------------------------------------------------
// MR_GNN: 2x (RGCN + GroupEnhance) + linear head.
// R3 -> R4: (a) gather_rel: quad-per-relation walk (no quad_reduce, one loop);
// (b) Group layers fused: gather+proj+residual (+head for layer 2) in one
// kernel, agg/g never hit global; (c) GEMM inner loop k-by-4 with float4 LDS
// reads on both operands; (d) scan_add dual-write kills the d2d memcpy.
// ---------------------------------------------------------------------------

__global__ void hist_dst(const int* __restrict__ ei, const int* __restrict__ et,
                         int* __restrict__ counts, int E) {
    int e = blockIdx.x * blockDim.x + threadIdx.x;
    if (e < E) atomicAdd(&counts[ei[E + e] * 4 + et[e]], 1);
}

// block-wise exclusive scan: 256 threads x 4 items = 1024 elements/block
__global__ __launch_bounds__(256) void scan_block(const int* __restrict__ in,
                                                  int* __restrict__ out,
                                                  int* __restrict__ bsum, int M) {
    __shared__ int lds[8];
    int base = blockIdx.x * 1024;
    int tid = threadIdx.x;
    int v[4];
    int s = 0;
#pragma unroll
    for (int j = 0; j < 4; ++j) {
        int i = base + tid * 4 + j;
        v[j] = (i < M) ? in[i] : 0;
        s += v[j];
    }
    int lane = tid & 63;
    int wid = tid >> 6;
    int ws = s;
#pragma unroll
    for (int off = 1; off < 64; off <<= 1) {
        int t = __shfl_up(ws, off);
        if (lane >= off) ws += t;
    }
    if (lane == 63) lds[wid] = ws;
    __syncthreads();
    if (tid == 0) {
        int a = 0;
        for (int w = 0; w < 4; ++w) { int t = lds[w]; lds[w] = a; a += t; }
        lds[4] = a;
    }
    __syncthreads();
    int excl = lds[wid] + ws - s;
#pragma unroll
    for (int j = 0; j < 4; ++j) {
        int i = base + tid * 4 + j;
        if (i < M) out[i] = excl;
        excl += v[j];
    }
    if (tid == 0) bsum[blockIdx.x] = lds[4];
}

__global__ __launch_bounds__(1024) void scan_tops(int* __restrict__ bsum, int nb) {
    __shared__ int lds[1024];
    int tid = threadIdx.x;
    int v = (tid < nb) ? bsum[tid] : 0;
    lds[tid] = v;
    __syncthreads();
    int acc = v;
    for (int off = 1; off < 1024; off <<= 1) {
        int t = (tid >= off) ? lds[tid - off] : 0;
        __syncthreads();
        acc += t;
        lds[tid] = acc;
        __syncthreads();
    }
    if (tid < nb) bsum[tid] = acc - v;  // exclusive
}

// finalize rp2 AND write the csr_fill cursor array (saves a d2d memcpy)
__global__ void scan_add2(int* __restrict__ rp, int* __restrict__ next,
                          const int* __restrict__ bsum, int M, int E) {
    int i = blockIdx.x * 256 + threadIdx.x;
    if (i < M) {
        int v = rp[i] + bsum[i >> 10];
        rp[i] = v;
        next[i] = v;
    }
    if (i == 0) rp[M] = E;
}

__global__ void csr_fill(const int* __restrict__ ei, const int* __restrict__ et,
                         const float* __restrict__ ew, int* __restrict__ next,
                         int2* __restrict__ pw, int E) {
    int e = blockIdx.x * 256 + threadIdx.x;
    if (e >= E) return;
    int pos = atomicAdd(&next[ei[E + e] * 4 + et[e]], 1);
    pw[pos] = make_int2(ei[e], __float_as_int(ew[e]));
}

__device__ __forceinline__ float4 quad_reduce(float4 a) {
#pragma unroll
    for (int off = 16; off < 64; off <<= 1) {
        a.x += __shfl_xor(a.x, off);
        a.y += __shfl_xor(a.y, off);
        a.z += __shfl_xor(a.z, off);
        a.w += __shfl_xor(a.w, off);
    }
    return a;
}

// one wave per node; quad q walks relation-segment q alone, its 16 lanes
// (x float4) cover the full 64-feature row -> no cross-lane reduction at all.
__global__ __launch_bounds__(256) void gather_rel(
    const float* __restrict__ X, const int* __restrict__ rp2,
    const int2* __restrict__ pw, float* __restrict__ aggR, int N) {
    int node = blockIdx.x * 4 + (threadIdx.x >> 6);
    if (node >= N) return;
    int lane = threadIdx.x & 63;
    int q = lane >> 4, m = lane & 15;
    int i = rp2[node * 4 + q], end = rp2[node * 4 + q + 1];
    float4 acc = make_float4(0.f, 0.f, 0.f, 0.f);
    for (; i + 1 < end; i += 2) {  // 2 independent gathers in flight
        int2 a = pw[i];
        int2 b = pw[i + 1];
        float4 xa = *reinterpret_cast<const float4*>(X + (size_t)a.x * 64 + m * 4);
        float4 xb = *reinterpret_cast<const float4*>(X + (size_t)b.x * 64 + m * 4);
        float wa = __int_as_float(a.y), wb = __int_as_float(b.y);
        acc.x += wa * xa.x; acc.y += wa * xa.y; acc.z += wa * xa.z; acc.w += wa * xa.w;
        acc.x += wb * xb.x; acc.y += wb * xb.y; acc.z += wb * xb.z; acc.w += wb * xb.w;
    }
    if (i < end) {
        int2 a = pw[i];
        float4 xa = *reinterpret_cast<const float4*>(X + (size_t)a.x * 64 + m * 4);
        float wa = __int_as_float(a.y);
        acc.x += wa * xa.x; acc.y += wa * xa.y; acc.z += wa * xa.z; acc.w += wa * xa.w;
    }
    *reinterpret_cast<float4*>(aggR + (size_t)node * 256 + q * 64 + m * 4) = acc;
}

// ---------------------------------------------------------------------------
// RGCN node GEMM: OUT = relu((X@W0 + [agg_r]@[W_r]) / deg),  [N x 320]@[320 x 64]
// k-by-4 inner loop, float4 LDS reads on both operands.
// ---------------------------------------------------------------------------
__global__ __launch_bounds__(256) void rgcn_gemm(
    const float* __restrict__ X, const float* __restrict__ AGG,
    const float* __restrict__ B0, const float* __restrict__ B1,
    const int* __restrict__ rp2, float* __restrict__ OUT, int N) {
    __shared__ float As[64][68];
    __shared__ float Bs[64][68];
    const int tid = threadIdx.x;
    const int tx = tid & 15, ty = tid >> 4;
    const int row0 = blockIdx.x * 64;
    float acc[4][4] = {};

    for (int c = 0; c < 5; ++c) {
        const float* A = (c == 0) ? X : AGG + (c - 1) * 64;
        const int lda = (c == 0) ? 64 : 256;
        const float* B = (c == 0) ? B0 : B1 + (size_t)(c - 1) * 64 * 64;
        if (c) __syncthreads();
#pragma unroll
        for (int qq = 0; qq < 4; ++qq) {
            int f = qq * 256 + tid;
            int r = f >> 4;
            int c4 = (f & 15) << 2;
            float4 v = make_float4(0.f, 0.f, 0.f, 0.f);
            int vr = row0 + r;
            if (vr < N) v = *reinterpret_cast<const float4*>(A + (size_t)vr * lda + c4);
            *reinterpret_cast<float4*>(&As[r][c4]) = v;
            *reinterpret_cast<float4*>(&Bs[r][c4]) =
                *reinterpret_cast<const float4*>(B + (size_t)r * 64 + c4);
        }
        __syncthreads();
#pragma unroll
        for (int k = 0; k < 64; k += 4) {
            float4 a0 = *reinterpret_cast<const float4*>(&As[ty * 4 + 0][k]);
            float4 a1 = *reinterpret_cast<const float4*>(&As[ty * 4 + 1][k]);
            float4 a2 = *reinterpret_cast<const float4*>(&As[ty * 4 + 2][k]);
            float4 a3 = *reinterpret_cast<const float4*>(&As[ty * 4 + 3][k]);
            float4 b0 = *reinterpret_cast<const float4*>(&Bs[k + 0][tx * 4]);
            float4 b1 = *reinterpret_cast<const float4*>(&Bs[k + 1][tx * 4]);
            float4 b2 = *reinterpret_cast<const float4*>(&Bs[k + 2][tx * 4]);
            float4 b3 = *reinterpret_cast<const float4*>(&Bs[k + 3][tx * 4]);
#define DOT4(ai, r) \
            acc[r][0] += ai.x * b0.x + ai.y * b1.x + ai.z * b2.x + ai.w * b3.x; \
            acc[r][1] += ai.x * b0.y + ai.y * b1.y + ai.z * b2.y + ai.w * b3.y; \
            acc[r][2] += ai.x * b0.z + ai.y * b1.z + ai.z * b2.z + ai.w * b3.z; \
            acc[r][3] += ai.x * b0.w + ai.y * b1.w + ai.z * b2.w + ai.w * b3.w;
            DOT4(a0, 0) DOT4(a1, 1) DOT4(a2, 2) DOT4(a3, 3)
#undef DOT4
        }
    }

#pragma unroll
    for (int i = 0; i < 4; ++i) {
        int vr = row0 + ty * 4 + i;
        if (vr >= N) continue;
        float dg = fmaxf((float)(rp2[vr * 4 + 4] - rp2[vr * 4]), 1.f);
        float4 o;
        o.x = fmaxf(acc[i][0] / dg, 0.f);
        o.y = fmaxf(acc[i][1] / dg, 0.f);
        o.z = fmaxf(acc[i][2] / dg, 0.f);
        o.w = fmaxf(acc[i][3] / dg, 0.f);
        *reinterpret_cast<float4*>(OUT + (size_t)vr * 64 + tx * 4) = o;
    }
}

// ---------------------------------------------------------------------------
// Fused GroupEnhance: gather (into LDS) + g = H + alpha*(agg@P/deg + pb).
// WITH_HEAD: also out = g @ outW + outb  (g never hits global).
// Block = 64 nodes; each wave gathers 16 nodes sequentially.
// ---------------------------------------------------------------------------
template <int WITH_HEAD>
__global__ __launch_bounds__(256) void group_fused(
    const float* __restrict__ H, const int* __restrict__ rp2,
    const int2* __restrict__ pw, const float* __restrict__ P,
    const float* __restrict__ pb, const float* __restrict__ alphap,
    const float* __restrict__ outW, const float* __restrict__ outb,
    float* __restrict__ OUT, int N) {
    __shared__ float Ag[64][68];
    __shared__ float Bs[64][68];
    const int tid = threadIdx.x;
    const int wave = tid >> 6, lane = tid & 63;
    const int q = lane >> 4, m = lane & 15;
    const int row0 = blockIdx.x * 64;

    // stage P while gathers are independent of Bs
#pragma unroll
    for (int qq = 0; qq < 4; ++qq) {
        int f = qq * 256 + tid;
        int r = f >> 4;
        int c4 = (f & 15) << 2;
        *reinterpret_cast<float4*>(&Bs[r][c4]) =
            *reinterpret_cast<const float4*>(P + (size_t)r * 64 + c4);
    }

    // gather: wave handles 16 nodes; edge-parallel quads + quad_reduce
#pragma unroll 1
    for (int t = 0; t < 16; ++t) {
        int node = row0 + wave * 16 + t;
        float4 acc = make_float4(0.f, 0.f, 0.f, 0.f);
        if (node < N) {
            int end = rp2[node * 4 + 4];
            int i = rp2[node * 4] + q;
            for (; i + 4 < end; i += 8) {
                int2 a = pw[i];
                int2 b = pw[i + 4];
                float4 xa = *reinterpret_cast<const float4*>(H + (size_t)a.x * 64 + m * 4);
                float4 xb = *reinterpret_cast<const float4*>(H + (size_t)b.x * 64 + m * 4);
                float wa = __int_as_float(a.y), wb = __int_as_float(b.y);
                acc.x += wa * xa.x; acc.y += wa * xa.y; acc.z += wa * xa.z; acc.w += wa * xa.w;
                acc.x += wb * xb.x; acc.y += wb * xb.y; acc.z += wb * xb.z; acc.w += wb * xb.w;
            }
            if (i < end) {
                int2 a = pw[i];
                float4 xa = *reinterpret_cast<const float4*>(H + (size_t)a.x * 64 + m * 4);
                float wa = __int_as_float(a.y);
                acc.x += wa * xa.x; acc.y += wa * xa.y; acc.z += wa * xa.z; acc.w += wa * xa.w;
            }
        }
        acc = quad_reduce(acc);
        if (q == 0 && node < N)
            *reinterpret_cast<float4*>(&Ag[wave * 16 + t][m * 4]) = acc;
    }
    __syncthreads();

    // proj GEMM [64x64]@[64x64]
    const int tx = tid & 15, ty = tid >> 4;
    float acc[4][4] = {};
#pragma unroll
    for (int k = 0; k < 64; k += 4) {
        float4 a0 = *reinterpret_cast<const float4*>(&Ag[ty * 4 + 0][k]);
        float4 a1 = *reinterpret_cast<const float4*>(&Ag[ty * 4 + 1][k]);
        float4 a2 = *reinterpret_cast<const float4*>(&Ag[ty * 4 + 2][k]);
        float4 a3 = *reinterpret_cast<const float4*>(&Ag[ty * 4 + 3][k]);
        float4 b0 = *reinterpret_cast<const float4*>(&Bs[k + 0][tx * 4]);
        float4 b1 = *reinterpret_cast<const float4*>(&Bs[k + 1][tx * 4]);
        float4 b2 = *reinterpret_cast<const float4*>(&Bs[k + 2][tx * 4]);
        float4 b3 = *reinterpret_cast<const float4*>(&Bs[k + 3][tx * 4]);
#define DOT4(ai, r) \
        acc[r][0] += ai.x * b0.x + ai.y * b1.x + ai.z * b2.x + ai.w * b3.x; \
        acc[r][1] += ai.x * b0.y + ai.y * b1.y + ai.z * b2.y + ai.w * b3.y; \
        acc[r][2] += ai.x * b0.z + ai.y * b1.z + ai.z * b2.z + ai.w * b3.z; \
        acc[r][3] += ai.x * b0.w + ai.y * b1.w + ai.z * b2.w + ai.w * b3.w;
        DOT4(a0, 0) DOT4(a1, 1) DOT4(a2, 2) DOT4(a3, 3)
#undef DOT4
    }

    const float alpha = alphap[0];
    float g[4][4];
#pragma unroll
    for (int i = 0; i < 4; ++i) {
        int vr = row0 + ty * 4 + i;
        if (vr >= N) continue;
        float dg = fmaxf((float)(rp2[vr * 4 + 4] - rp2[vr * 4]), 1.f);
        float4 h = *reinterpret_cast<const float4*>(H + (size_t)vr * 64 + tx * 4);
        g[i][0] = h.x + alpha * (acc[i][0] / dg + pb[tx * 4 + 0]);
        g[i][1] = h.y + alpha * (acc[i][1] / dg + pb[tx * 4 + 1]);
        g[i][2] = h.z + alpha * (acc[i][2] / dg + pb[tx * 4 + 2]);
        g[i][3] = h.w + alpha * (acc[i][3] / dg + pb[tx * 4 + 3]);
        if (!WITH_HEAD)
            *reinterpret_cast<float4*>(OUT + (size_t)vr * 64 + tx * 4) =
                make_float4(g[i][0], g[i][1], g[i][2], g[i][3]);
    }

    if (WITH_HEAD) {
        __syncthreads();  // everyone done reading Ag/Bs
        // Gs (=Ag) <- g ; Bs <- outW [64x32]
#pragma unroll
        for (int i = 0; i < 4; ++i) {
            int vr = row0 + ty * 4 + i;
            if (vr < N)
                *reinterpret_cast<float4*>(&Ag[ty * 4 + i][tx * 4]) =
                    make_float4(g[i][0], g[i][1], g[i][2], g[i][3]);
        }
#pragma unroll
        for (int qq = 0; qq < 2; ++qq) {
            int f = qq * 256 + tid;
            int r = f >> 3;
            int c4 = (f & 7) << 2;
            *reinterpret_cast<float4*>(&Bs[r][c4]) =
                *reinterpret_cast<const float4*>(outW + (size_t)r * 32 + c4);
        }
        __syncthreads();
        // head GEMM [64x64]@[64x32]: 2 rows x 4 cols per thread
        const int tx2 = tid & 7, ty2 = tid >> 3;
        float acc2[2][4] = {};
#pragma unroll
        for (int k = 0; k < 64; k += 4) {
            float4 b0 = *reinterpret_cast<const float4*>(&Bs[k + 0][tx2 * 4]);
            float4 b1 = *reinterpret_cast<const float4*>(&Bs[k + 1][tx2 * 4]);
            float4 b2 = *reinterpret_cast<const float4*>(&Bs[k + 2][tx2 * 4]);
            float4 b3 = *reinterpret_cast<const float4*>(&Bs[k + 3][tx2 * 4]);
#pragma unroll
            for (int i = 0; i < 2; ++i) {
                float4 a = *reinterpret_cast<const float4*>(&Ag[ty2 * 2 + i][k]);
                acc2[i][0] += a.x * b0.x + a.y * b1.x + a.z * b2.x + a.w * b3.x;
                acc2[i][1] += a.x * b0.y + a.y * b1.y + a.z * b2.y + a.w * b3.y;
                acc2[i][2] += a.x * b0.z + a.y * b1.z + a.z * b2.z + a.w * b3.z;
                acc2[i][3] += a.x * b0.w + a.y * b1.w + a.z * b2.w + a.w * b3.w;
            }
        }
#pragma unroll
        for (int i = 0; i < 2; ++i) {
            int vr = row0 + ty2 * 2 + i;
            if (vr >= N) continue;
            float4 o;
            o.x = acc2[i][0] + outb[tx2 * 4 + 0];
            o.y = acc2[i][1] + outb[tx2 * 4 + 1];
            o.z = acc2[i][2] + outb[tx2 * 4 + 2];
            o.w = acc2[i][3] + outb[tx2 * 4 + 3];
            *reinterpret_cast<float4*>(OUT + (size_t)vr * 32 + tx2 * 4) = o;
        }
    }
}

extern "C" void kernel_launch(void* const* d_in, const int* in_sizes, int n_in,
                              void* d_out, int out_size, void* d_ws, size_t ws_size,
                              hipStream_t stream) {
    const float* x      = (const float*)d_in[0];
    const int*   ei     = (const int*)d_in[1];
    const int*   et     = (const int*)d_in[2];
    const float* ew     = (const float*)d_in[3];
    const float* W1     = (const float*)d_in[4];
    const float* W01    = (const float*)d_in[5];
    const float* alpha1 = (const float*)d_in[6];
    const float* projW1 = (const float*)d_in[7];
    const float* projb1 = (const float*)d_in[8];
    const float* W2     = (const float*)d_in[9];
    const float* W02    = (const float*)d_in[10];
    const float* alpha2 = (const float*)d_in[11];
    const float* projW2 = (const float*)d_in[12];
    const float* projb2 = (const float*)d_in[13];
    const float* outW   = (const float*)d_in[14];
    const float* outb   = (const float*)d_in[15];
    const int N = in_sizes[0] / 64;
    const int E = in_sizes[2];
    const int M = 4 * N;

    // workspace (4-byte units):
    // counts4/next4[M] | rp2[M+1] | bsum[1024] | pw int2[E] | aggR[N*256]
    // | h[N*64] | g[N*64]
    int*   counts4 = (int*)d_ws;
    int*   rp2     = counts4 + M;
    int*   bsum    = rp2 + M + 1;
    int2*  pw      = (int2*)(bsum + 1024);
    float* aggR    = (float*)(pw + E);
    float* hbuf    = aggR + (size_t)N * 256;
    float* gbuf    = hbuf + (size_t)N * 64;

    const int nb = (M + 1023) / 1024;
    const int gatherBlocks = (N + 3) / 4;
    const int gemmBlocks = (N + 63) / 64;
    const int eBlocks = (E + 255) / 256;

    // ---- CSR build (once per call) ----
    hipMemsetAsync(counts4, 0, (size_t)M * 4, stream);
    hist_dst<<<eBlocks, 256, 0, stream>>>(ei, et, counts4, E);
    scan_block<<<nb, 256, 0, stream>>>(counts4, rp2, bsum, M);
    scan_tops<<<1, 1024, 0, stream>>>(bsum, nb);
    scan_add2<<<(M + 255) / 256, 256, 0, stream>>>(rp2, counts4, bsum, M, E);
    csr_fill<<<eBlocks, 256, 0, stream>>>(ei, et, ew, counts4, pw, E);

    // ---- layer 1 ----
    gather_rel<<<gatherBlocks, 256, 0, stream>>>(x, rp2, pw, aggR, N);
    rgcn_gemm<<<gemmBlocks, 256, 0, stream>>>(x, aggR, W01, W1, rp2, hbuf, N);
    group_fused<0><<<gemmBlocks, 256, 0, stream>>>(hbuf, rp2, pw, projW1, projb1,
                                                   alpha1, nullptr, nullptr, gbuf, N);

    // ---- layer 2 ----
    gather_rel<<<gatherBlocks, 256, 0, stream>>>(gbuf, rp2, pw, aggR, N);
    rgcn_gemm<<<gemmBlocks, 256, 0, stream>>>(gbuf, aggR, W02, W2, rp2, hbuf, N);
    group_fused<1><<<gemmBlocks, 256, 0, stream>>>(hbuf, rp2, pw, projW2, projb2,
                                                   alpha2, outW, outb, (float*)d_out, N);
}

// Round 5
// 606.474 us; speedup vs baseline: 1.4472x; 1.4472x over previous
//
#include <hip/hip_runtime.h>

// ---------------------------------------------------------------------------
// MR_GNN: 2x (RGCN + GroupEnhance) + linear head.
// R4 -> R5: un-fuse (R4's group_fused hit 256 VGPR / 8.9% occupancy -> 240us).
// Group layers restructured via linearity: HP = H@P first (dense GEMM), then
// a single gather over HP with the residual+bias epilogue fused. Layer-2
// group+head collapse into one GEMM (B2=[outW | P2@outW]) + one 128B-row
// gather. Keeps R4's quad-per-relation gather_rel, scan_add2, k-by-4 GEMMs.
// ---------------------------------------------------------------------------

__global__ void hist_dst(const int* __restrict__ ei, const int* __restrict__ et,
                         int* __restrict__ counts, int E) {
    int e = blockIdx.x * blockDim.x + threadIdx.x;
    if (e < E) atomicAdd(&counts[ei[E + e] * 4 + et[e]], 1);
}

// block-wise exclusive scan: 256 threads x 4 items = 1024 elements/block
__global__ __launch_bounds__(256) void scan_block(const int* __restrict__ in,
                                                  int* __restrict__ out,
                                                  int* __restrict__ bsum, int M) {
    __shared__ int lds[8];
    int base = blockIdx.x * 1024;
    int tid = threadIdx.x;
    int v[4];
    int s = 0;
#pragma unroll
    for (int j = 0; j < 4; ++j) {
        int i = base + tid * 4 + j;
        v[j] = (i < M) ? in[i] : 0;
        s += v[j];
    }
    int lane = tid & 63;
    int wid = tid >> 6;
    int ws = s;
#pragma unroll
    for (int off = 1; off < 64; off <<= 1) {
        int t = __shfl_up(ws, off);
        if (lane >= off) ws += t;
    }
    if (lane == 63) lds[wid] = ws;
    __syncthreads();
    if (tid == 0) {
        int a = 0;
        for (int w = 0; w < 4; ++w) { int t = lds[w]; lds[w] = a; a += t; }
        lds[4] = a;
    }
    __syncthreads();
    int excl = lds[wid] + ws - s;
#pragma unroll
    for (int j = 0; j < 4; ++j) {
        int i = base + tid * 4 + j;
        if (i < M) out[i] = excl;
        excl += v[j];
    }
    if (tid == 0) bsum[blockIdx.x] = lds[4];
}

__global__ __launch_bounds__(1024) void scan_tops(int* __restrict__ bsum, int nb) {
    __shared__ int lds[1024];
    int tid = threadIdx.x;
    int v = (tid < nb) ? bsum[tid] : 0;
    lds[tid] = v;
    __syncthreads();
    int acc = v;
    for (int off = 1; off < 1024; off <<= 1) {
        int t = (tid >= off) ? lds[tid - off] : 0;
        __syncthreads();
        acc += t;
        lds[tid] = acc;
        __syncthreads();
    }
    if (tid < nb) bsum[tid] = acc - v;  // exclusive
}

// finalize rp2 AND write the csr_fill cursor array (saves a d2d memcpy)
__global__ void scan_add2(int* __restrict__ rp, int* __restrict__ next,
                          const int* __restrict__ bsum, int M, int E) {
    int i = blockIdx.x * 256 + threadIdx.x;
    if (i < M) {
        int v = rp[i] + bsum[i >> 10];
        rp[i] = v;
        next[i] = v;
    }
    if (i == 0) rp[M] = E;
}

__global__ void csr_fill(const int* __restrict__ ei, const int* __restrict__ et,
                         const float* __restrict__ ew, int* __restrict__ next,
                         int2* __restrict__ pw, int E) {
    int e = blockIdx.x * 256 + threadIdx.x;
    if (e >= E) return;
    int pos = atomicAdd(&next[ei[E + e] * 4 + et[e]], 1);
    pw[pos] = make_int2(ei[e], __float_as_int(ew[e]));
}

// one wave per node; quad q walks relation-segment q alone, its 16 lanes
// (x float4) cover the full 64-feature row -> no cross-lane reduction.
__global__ __launch_bounds__(256) void gather_rel(
    const float* __restrict__ X, const int* __restrict__ rp2,
    const int2* __restrict__ pw, float* __restrict__ aggR, int N) {
    int node = blockIdx.x * 4 + (threadIdx.x >> 6);
    if (node >= N) return;
    int lane = threadIdx.x & 63;
    int q = lane >> 4, m = lane & 15;
    int i = rp2[node * 4 + q], end = rp2[node * 4 + q + 1];
    float4 acc = make_float4(0.f, 0.f, 0.f, 0.f);
    for (; i + 1 < end; i += 2) {
        int2 a = pw[i];
        int2 b = pw[i + 1];
        float4 xa = *reinterpret_cast<const float4*>(X + (size_t)a.x * 64 + m * 4);
        float4 xb = *reinterpret_cast<const float4*>(X + (size_t)b.x * 64 + m * 4);
        float wa = __int_as_float(a.y), wb = __int_as_float(b.y);
        acc.x += wa * xa.x; acc.y += wa * xa.y; acc.z += wa * xa.z; acc.w += wa * xa.w;
        acc.x += wb * xb.x; acc.y += wb * xb.y; acc.z += wb * xb.z; acc.w += wb * xb.w;
    }
    if (i < end) {
        int2 a = pw[i];
        float4 xa = *reinterpret_cast<const float4*>(X + (size_t)a.x * 64 + m * 4);
        float wa = __int_as_float(a.y);
        acc.x += wa * xa.x; acc.y += wa * xa.y; acc.z += wa * xa.z; acc.w += wa * xa.w;
    }
    *reinterpret_cast<float4*>(aggR + (size_t)node * 256 + q * 64 + m * 4) = acc;
}

// ---------------------------------------------------------------------------
// RGCN node GEMM: OUT = relu((X@W0 + [agg_r]@[W_r]) / deg),  [N x 320]@[320 x 64]
// ---------------------------------------------------------------------------
__global__ __launch_bounds__(256) void rgcn_gemm(
    const float* __restrict__ X, const float* __restrict__ AGG,
    const float* __restrict__ B0, const float* __restrict__ B1,
    const int* __restrict__ rp2, float* __restrict__ OUT, int N) {
    __shared__ float As[64][68];
    __shared__ float Bs[64][68];
    const int tid = threadIdx.x;
    const int tx = tid & 15, ty = tid >> 4;
    const int row0 = blockIdx.x * 64;
    float acc[4][4] = {};

    for (int c = 0; c < 5; ++c) {
        const float* A = (c == 0) ? X : AGG + (c - 1) * 64;
        const int lda = (c == 0) ? 64 : 256;
        const float* B = (c == 0) ? B0 : B1 + (size_t)(c - 1) * 64 * 64;
        if (c) __syncthreads();
#pragma unroll
        for (int qq = 0; qq < 4; ++qq) {
            int f = qq * 256 + tid;
            int r = f >> 4;
            int c4 = (f & 15) << 2;
            float4 v = make_float4(0.f, 0.f, 0.f, 0.f);
            int vr = row0 + r;
            if (vr < N) v = *reinterpret_cast<const float4*>(A + (size_t)vr * lda + c4);
            *reinterpret_cast<float4*>(&As[r][c4]) = v;
            *reinterpret_cast<float4*>(&Bs[r][c4]) =
                *reinterpret_cast<const float4*>(B + (size_t)r * 64 + c4);
        }
        __syncthreads();
#pragma unroll
        for (int k = 0; k < 64; k += 4) {
            float4 a0 = *reinterpret_cast<const float4*>(&As[ty * 4 + 0][k]);
            float4 a1 = *reinterpret_cast<const float4*>(&As[ty * 4 + 1][k]);
            float4 a2 = *reinterpret_cast<const float4*>(&As[ty * 4 + 2][k]);
            float4 a3 = *reinterpret_cast<const float4*>(&As[ty * 4 + 3][k]);
            float4 b0 = *reinterpret_cast<const float4*>(&Bs[k + 0][tx * 4]);
            float4 b1 = *reinterpret_cast<const float4*>(&Bs[k + 1][tx * 4]);
            float4 b2 = *reinterpret_cast<const float4*>(&Bs[k + 2][tx * 4]);
            float4 b3 = *reinterpret_cast<const float4*>(&Bs[k + 3][tx * 4]);
#define DOT4(ai, r) \
            acc[r][0] += ai.x * b0.x + ai.y * b1.x + ai.z * b2.x + ai.w * b3.x; \
            acc[r][1] += ai.x * b0.y + ai.y * b1.y + ai.z * b2.y + ai.w * b3.y; \
            acc[r][2] += ai.x * b0.z + ai.y * b1.z + ai.z * b2.z + ai.w * b3.z; \
            acc[r][3] += ai.x * b0.w + ai.y * b1.w + ai.z * b2.w + ai.w * b3.w;
            DOT4(a0, 0) DOT4(a1, 1) DOT4(a2, 2) DOT4(a3, 3)
#undef DOT4
        }
    }

#pragma unroll
    for (int i = 0; i < 4; ++i) {
        int vr = row0 + ty * 4 + i;
        if (vr >= N) continue;
        float dg = fmaxf((float)(rp2[vr * 4 + 4] - rp2[vr * 4]), 1.f);
        float4 o;
        o.x = fmaxf(acc[i][0] / dg, 0.f);
        o.y = fmaxf(acc[i][1] / dg, 0.f);
        o.z = fmaxf(acc[i][2] / dg, 0.f);
        o.w = fmaxf(acc[i][3] / dg, 0.f);
        *reinterpret_cast<float4*>(OUT + (size_t)vr * 64 + tx * 4) = o;
    }
}

// plain OUT = A @ B, A:[N x 64], B:[64 x 64]
__global__ __launch_bounds__(256) void gemm64(
    const float* __restrict__ A, const float* __restrict__ B,
    float* __restrict__ OUT, int N) {
    __shared__ float As[64][68];
    __shared__ float Bs[64][68];
    const int tid = threadIdx.x;
    const int tx = tid & 15, ty = tid >> 4;
    const int row0 = blockIdx.x * 64;
    float acc[4][4] = {};
#pragma unroll
    for (int qq = 0; qq < 4; ++qq) {
        int f = qq * 256 + tid;
        int r = f >> 4;
        int c4 = (f & 15) << 2;
        float4 v = make_float4(0.f, 0.f, 0.f, 0.f);
        int vr = row0 + r;
        if (vr < N) v = *reinterpret_cast<const float4*>(A + (size_t)vr * 64 + c4);
        *reinterpret_cast<float4*>(&As[r][c4]) = v;
        *reinterpret_cast<float4*>(&Bs[r][c4]) =
            *reinterpret_cast<const float4*>(B + (size_t)r * 64 + c4);
    }
    __syncthreads();
#pragma unroll
    for (int k = 0; k < 64; k += 4) {
        float4 a0 = *reinterpret_cast<const float4*>(&As[ty * 4 + 0][k]);
        float4 a1 = *reinterpret_cast<const float4*>(&As[ty * 4 + 1][k]);
        float4 a2 = *reinterpret_cast<const float4*>(&As[ty * 4 + 2][k]);
        float4 a3 = *reinterpret_cast<const float4*>(&As[ty * 4 + 3][k]);
        float4 b0 = *reinterpret_cast<const float4*>(&Bs[k + 0][tx * 4]);
        float4 b1 = *reinterpret_cast<const float4*>(&Bs[k + 1][tx * 4]);
        float4 b2 = *reinterpret_cast<const float4*>(&Bs[k + 2][tx * 4]);
        float4 b3 = *reinterpret_cast<const float4*>(&Bs[k + 3][tx * 4]);
#define DOT4(ai, r) \
        acc[r][0] += ai.x * b0.x + ai.y * b1.x + ai.z * b2.x + ai.w * b3.x; \
        acc[r][1] += ai.x * b0.y + ai.y * b1.y + ai.z * b2.y + ai.w * b3.y; \
        acc[r][2] += ai.x * b0.z + ai.y * b1.z + ai.z * b2.z + ai.w * b3.z; \
        acc[r][3] += ai.x * b0.w + ai.y * b1.w + ai.z * b2.w + ai.w * b3.w;
        DOT4(a0, 0) DOT4(a1, 1) DOT4(a2, 2) DOT4(a3, 3)
#undef DOT4
    }
#pragma unroll
    for (int i = 0; i < 4; ++i) {
        int vr = row0 + ty * 4 + i;
        if (vr >= N) continue;
        *reinterpret_cast<float4*>(OUT + (size_t)vr * 64 + tx * 4) =
            make_float4(acc[i][0], acc[i][1], acc[i][2], acc[i][3]);
    }
}

// one block: b2[64][64] = [outW | P2@outW]; b2[4096+j] = alpha2*(pb2@outW)[j]+outb[j]
__global__ __launch_bounds__(256) void prep_b2(
    const float* __restrict__ P2, const float* __restrict__ outW,
    const float* __restrict__ pb2, const float* __restrict__ alphap,
    const float* __restrict__ outb, float* __restrict__ b2) {
    int tid = threadIdx.x;
    int r = tid >> 2;            // 0..63
    int j0 = (tid & 3) * 8;      // 0,8,16,24
    float acc[8] = {};
    for (int k = 0; k < 64; ++k) {
        float p = P2[r * 64 + k];
#pragma unroll
        for (int jj = 0; jj < 8; ++jj) acc[jj] += p * outW[k * 32 + j0 + jj];
    }
#pragma unroll
    for (int jj = 0; jj < 8; ++jj) {
        b2[r * 64 + 32 + j0 + jj] = acc[jj];
        b2[r * 64 + j0 + jj] = outW[r * 32 + j0 + jj];
    }
    if (tid < 32) {
        float c = 0.f;
        for (int k = 0; k < 64; ++k) c += pb2[k] * outW[k * 32 + tid];
        b2[4096 + tid] = alphap[0] * c + outb[tid];
    }
}

// g[v] = H[v] + alpha*((sum_e w_e HP[src_e])/deg + pb)   -- one wave per node,
// quads edge-parallel (stride 4, 2x unroll), shfl_xor(16,32) reduce.
__global__ __launch_bounds__(256) void gather_res(
    const float* __restrict__ HP, const float* __restrict__ H,
    const int* __restrict__ rp2, const int2* __restrict__ pw,
    const float* __restrict__ pb, const float* __restrict__ alphap,
    float* __restrict__ G, int N) {
    int node = blockIdx.x * 4 + (threadIdx.x >> 6);
    if (node >= N) return;
    int lane = threadIdx.x & 63;
    int q = lane >> 4, m = lane & 15;
    int beg = rp2[node * 4], end = rp2[node * 4 + 4];
    float4 acc = make_float4(0.f, 0.f, 0.f, 0.f);
    int i = beg + q;
    for (; i + 4 < end; i += 8) {
        int2 a = pw[i];
        int2 b = pw[i + 4];
        float4 xa = *reinterpret_cast<const float4*>(HP + (size_t)a.x * 64 + m * 4);
        float4 xb = *reinterpret_cast<const float4*>(HP + (size_t)b.x * 64 + m * 4);
        float wa = __int_as_float(a.y), wb = __int_as_float(b.y);
        acc.x += wa * xa.x; acc.y += wa * xa.y; acc.z += wa * xa.z; acc.w += wa * xa.w;
        acc.x += wb * xb.x; acc.y += wb * xb.y; acc.z += wb * xb.z; acc.w += wb * xb.w;
    }
    if (i < end) {
        int2 a = pw[i];
        float4 xa = *reinterpret_cast<const float4*>(HP + (size_t)a.x * 64 + m * 4);
        float wa = __int_as_float(a.y);
        acc.x += wa * xa.x; acc.y += wa * xa.y; acc.z += wa * xa.z; acc.w += wa * xa.w;
    }
#pragma unroll
    for (int off = 16; off < 64; off <<= 1) {
        acc.x += __shfl_xor(acc.x, off);
        acc.y += __shfl_xor(acc.y, off);
        acc.z += __shfl_xor(acc.z, off);
        acc.w += __shfl_xor(acc.w, off);
    }
    if (q == 0) {
        float inv = 1.f / fmaxf((float)(end - beg), 1.f);
        float alpha = alphap[0];
        float4 h = *reinterpret_cast<const float4*>(H + (size_t)node * 64 + m * 4);
        float4 pbv = *reinterpret_cast<const float4*>(pb + m * 4);
        float4 o;
        o.x = h.x + alpha * (acc.x * inv + pbv.x);
        o.y = h.y + alpha * (acc.y * inv + pbv.y);
        o.z = h.z + alpha * (acc.z * inv + pbv.z);
        o.w = h.w + alpha * (acc.w * inv + pbv.w);
        *reinterpret_cast<float4*>(G + (size_t)node * 64 + m * 4) = o;
    }
}

// out[v] = U[v] + alpha*(sum_e w_e T[src_e])/deg + c,  UT[v] = [U(32) | T(32)].
// one wave per node, 8 octs edge-parallel (8 gathers in flight), 128B rows.
__global__ __launch_bounds__(256) void gather_res_head(
    const float* __restrict__ UT, const int* __restrict__ rp2,
    const int2* __restrict__ pw, const float* __restrict__ b2,
    const float* __restrict__ alphap, float* __restrict__ OUT, int N) {
    int node = blockIdx.x * 4 + (threadIdx.x >> 6);
    if (node >= N) return;
    int lane = threadIdx.x & 63;
    int oct = lane >> 3, m = lane & 7;
    int beg = rp2[node * 4], end = rp2[node * 4 + 4];
    float4 acc = make_float4(0.f, 0.f, 0.f, 0.f);
    for (int i = beg + oct; i < end; i += 8) {
        int2 a = pw[i];
        float4 t = *reinterpret_cast<const float4*>(UT + (size_t)a.x * 64 + 32 + m * 4);
        float w = __int_as_float(a.y);
        acc.x += w * t.x; acc.y += w * t.y; acc.z += w * t.z; acc.w += w * t.w;
    }
#pragma unroll
    for (int off = 8; off < 64; off <<= 1) {
        acc.x += __shfl_xor(acc.x, off);
        acc.y += __shfl_xor(acc.y, off);
        acc.z += __shfl_xor(acc.z, off);
        acc.w += __shfl_xor(acc.w, off);
    }
    if (oct == 0) {
        float s = alphap[0] / fmaxf((float)(end - beg), 1.f);
        float4 u = *reinterpret_cast<const float4*>(UT + (size_t)node * 64 + m * 4);
        float4 cv = *reinterpret_cast<const float4*>(b2 + 4096 + m * 4);
        float4 o;
        o.x = u.x + s * acc.x + cv.x;
        o.y = u.y + s * acc.y + cv.y;
        o.z = u.z + s * acc.z + cv.z;
        o.w = u.w + s * acc.w + cv.w;
        *reinterpret_cast<float4*>(OUT + (size_t)node * 32 + m * 4) = o;
    }
}

extern "C" void kernel_launch(void* const* d_in, const int* in_sizes, int n_in,
                              void* d_out, int out_size, void* d_ws, size_t ws_size,
                              hipStream_t stream) {
    const float* x      = (const float*)d_in[0];
    const int*   ei     = (const int*)d_in[1];
    const int*   et     = (const int*)d_in[2];
    const float* ew     = (const float*)d_in[3];
    const float* W1     = (const float*)d_in[4];
    const float* W01    = (const float*)d_in[5];
    const float* alpha1 = (const float*)d_in[6];
    const float* projW1 = (const float*)d_in[7];
    const float* projb1 = (const float*)d_in[8];
    const float* W2     = (const float*)d_in[9];
    const float* W02    = (const float*)d_in[10];
    const float* alpha2 = (const float*)d_in[11];
    const float* projW2 = (const float*)d_in[12];
    const float* projb2 = (const float*)d_in[13];
    const float* outW   = (const float*)d_in[14];
    const float* outb   = (const float*)d_in[15];
    const int N = in_sizes[0] / 64;
    const int E = in_sizes[2];
    const int M = 4 * N;

    // workspace (4-byte units):
    // counts4/next4[M] | rp2[M+1] | bsum[1024] | pw int2[E] | b2[4096+32]
    // | aggR[N*256] (reused: HP overlay after rgcn consumes it; UT in layer 2)
    // | h[N*64] | g[N*64]     (~87 MB)
    int*   counts4 = (int*)d_ws;
    int*   rp2     = counts4 + M;
    int*   bsum    = rp2 + M + 1;
    int2*  pw      = (int2*)(bsum + 1024);
    float* b2      = (float*)(pw + E);
    float* aggR    = b2 + 4096 + 64;
    float* hbuf    = aggR + (size_t)N * 256;
    float* gbuf    = hbuf + (size_t)N * 64;
    float* hpbuf   = aggR;   // overlay: aggR is dead once rgcn_gemm has run
    float* utbuf   = aggR;

    const int nb = (M + 1023) / 1024;
    const int gatherBlocks = (N + 3) / 4;
    const int gemmBlocks = (N + 63) / 64;
    const int eBlocks = (E + 255) / 256;

    // ---- CSR build (once per call) ----
    hipMemsetAsync(counts4, 0, (size_t)M * 4, stream);
    hist_dst<<<eBlocks, 256, 0, stream>>>(ei, et, counts4, E);
    scan_block<<<nb, 256, 0, stream>>>(counts4, rp2, bsum, M);
    scan_tops<<<1, 1024, 0, stream>>>(bsum, nb);
    scan_add2<<<(M + 255) / 256, 256, 0, stream>>>(rp2, counts4, bsum, M, E);
    csr_fill<<<eBlocks, 256, 0, stream>>>(ei, et, ew, counts4, pw, E);
    prep_b2<<<1, 256, 0, stream>>>(projW2, outW, projb2, alpha2, outb, b2);

    // ---- layer 1 ----
    gather_rel<<<gatherBlocks, 256, 0, stream>>>(x, rp2, pw, aggR, N);
    rgcn_gemm<<<gemmBlocks, 256, 0, stream>>>(x, aggR, W01, W1, rp2, hbuf, N);
    gemm64<<<gemmBlocks, 256, 0, stream>>>(hbuf, projW1, hpbuf, N);           // HP = h@P1
    gather_res<<<gatherBlocks, 256, 0, stream>>>(hpbuf, hbuf, rp2, pw, projb1, alpha1, gbuf, N);

    // ---- layer 2 ----
    gather_rel<<<gatherBlocks, 256, 0, stream>>>(gbuf, rp2, pw, aggR, N);
    rgcn_gemm<<<gemmBlocks, 256, 0, stream>>>(gbuf, aggR, W02, W2, rp2, hbuf, N);
    gemm64<<<gemmBlocks, 256, 0, stream>>>(hbuf, b2, utbuf, N);               // UT = h@[outW|P2@outW]
    gather_res_head<<<gatherBlocks, 256, 0, stream>>>(utbuf, rp2, pw, b2, alpha2, (float*)d_out, N);
}

// Round 6
// 518.293 us; speedup vs baseline: 1.6934x; 1.1701x over previous
//
#include <hip/hip_runtime.h>

// ---------------------------------------------------------------------------
// MR_GNN: 2x (RGCN + GroupEnhance) + linear head.
// R5 -> R6: GEMMs were LDS-pipe-bound (8 ds_read_b128 per 64 FMA = 1 B/FLOP
// vs 85 B/cyc/CU LDS ceiling; FMA floor is only ~13us for 2.05 GF).
// New GEMM: A read directly from global (L1/L2-resident 16 KB chunks,
// broadcast-friendly, VMEM pipe was idle), B-only LDS double-buffered via
// registers (1 barrier/chunk), __launch_bounds__(256,4) for 16 waves/CU.
// CSR build + all gather kernels unchanged from R5 (passed, fetch-bound).
// ---------------------------------------------------------------------------

__global__ void hist_dst(const int* __restrict__ ei, const int* __restrict__ et,
                         int* __restrict__ counts, int E) {
    int e = blockIdx.x * blockDim.x + threadIdx.x;
    if (e < E) atomicAdd(&counts[ei[E + e] * 4 + et[e]], 1);
}

// block-wise exclusive scan: 256 threads x 4 items = 1024 elements/block
__global__ __launch_bounds__(256) void scan_block(const int* __restrict__ in,
                                                  int* __restrict__ out,
                                                  int* __restrict__ bsum, int M) {
    __shared__ int lds[8];
    int base = blockIdx.x * 1024;
    int tid = threadIdx.x;
    int v[4];
    int s = 0;
#pragma unroll
    for (int j = 0; j < 4; ++j) {
        int i = base + tid * 4 + j;
        v[j] = (i < M) ? in[i] : 0;
        s += v[j];
    }
    int lane = tid & 63;
    int wid = tid >> 6;
    int ws = s;
#pragma unroll
    for (int off = 1; off < 64; off <<= 1) {
        int t = __shfl_up(ws, off);
        if (lane >= off) ws += t;
    }
    if (lane == 63) lds[wid] = ws;
    __syncthreads();
    if (tid == 0) {
        int a = 0;
        for (int w = 0; w < 4; ++w) { int t = lds[w]; lds[w] = a; a += t; }
        lds[4] = a;
    }
    __syncthreads();
    int excl = lds[wid] + ws - s;
#pragma unroll
    for (int j = 0; j < 4; ++j) {
        int i = base + tid * 4 + j;
        if (i < M) out[i] = excl;
        excl += v[j];
    }
    if (tid == 0) bsum[blockIdx.x] = lds[4];
}

__global__ __launch_bounds__(1024) void scan_tops(int* __restrict__ bsum, int nb) {
    __shared__ int lds[1024];
    int tid = threadIdx.x;
    int v = (tid < nb) ? bsum[tid] : 0;
    lds[tid] = v;
    __syncthreads();
    int acc = v;
    for (int off = 1; off < 1024; off <<= 1) {
        int t = (tid >= off) ? lds[tid - off] : 0;
        __syncthreads();
        acc += t;
        lds[tid] = acc;
        __syncthreads();
    }
    if (tid < nb) bsum[tid] = acc - v;  // exclusive
}

// finalize rp2 AND write the csr_fill cursor array
__global__ void scan_add2(int* __restrict__ rp, int* __restrict__ next,
                          const int* __restrict__ bsum, int M, int E) {
    int i = blockIdx.x * 256 + threadIdx.x;
    if (i < M) {
        int v = rp[i] + bsum[i >> 10];
        rp[i] = v;
        next[i] = v;
    }
    if (i == 0) rp[M] = E;
}

__global__ void csr_fill(const int* __restrict__ ei, const int* __restrict__ et,
                         const float* __restrict__ ew, int* __restrict__ next,
                         int2* __restrict__ pw, int E) {
    int e = blockIdx.x * 256 + threadIdx.x;
    if (e >= E) return;
    int pos = atomicAdd(&next[ei[E + e] * 4 + et[e]], 1);
    pw[pos] = make_int2(ei[e], __float_as_int(ew[e]));
}

// one wave per node; quad q walks relation-segment q alone
__global__ __launch_bounds__(256) void gather_rel(
    const float* __restrict__ X, const int* __restrict__ rp2,
    const int2* __restrict__ pw, float* __restrict__ aggR, int N) {
    int node = blockIdx.x * 4 + (threadIdx.x >> 6);
    if (node >= N) return;
    int lane = threadIdx.x & 63;
    int q = lane >> 4, m = lane & 15;
    int i = rp2[node * 4 + q], end = rp2[node * 4 + q + 1];
    float4 acc = make_float4(0.f, 0.f, 0.f, 0.f);
    for (; i + 1 < end; i += 2) {
        int2 a = pw[i];
        int2 b = pw[i + 1];
        float4 xa = *reinterpret_cast<const float4*>(X + (size_t)a.x * 64 + m * 4);
        float4 xb = *reinterpret_cast<const float4*>(X + (size_t)b.x * 64 + m * 4);
        float wa = __int_as_float(a.y), wb = __int_as_float(b.y);
        acc.x += wa * xa.x; acc.y += wa * xa.y; acc.z += wa * xa.z; acc.w += wa * xa.w;
        acc.x += wb * xb.x; acc.y += wb * xb.y; acc.z += wb * xb.z; acc.w += wb * xb.w;
    }
    if (i < end) {
        int2 a = pw[i];
        float4 xa = *reinterpret_cast<const float4*>(X + (size_t)a.x * 64 + m * 4);
        float wa = __int_as_float(a.y);
        acc.x += wa * xa.x; acc.y += wa * xa.y; acc.z += wa * xa.z; acc.w += wa * xa.w;
    }
    *reinterpret_cast<float4*>(aggR + (size_t)node * 256 + q * 64 + m * 4) = acc;
}

// ---------------------------------------------------------------------------
// RGCN GEMM v2: OUT = relu((X@B0 + AGG@B1)/deg). A from global (L1-resident
// 16 KB chunks, 16-lane broadcast), B-only LDS double-buffered via regs.
// ---------------------------------------------------------------------------
__global__ __launch_bounds__(256, 4) void rgcn_gemm(
    const float* __restrict__ X, const float* __restrict__ AGG,
    const float* __restrict__ B0, const float* __restrict__ B1,
    const int* __restrict__ rp2, float* __restrict__ OUT, int N) {
    __shared__ float Bs[2][64][68];
    const int tid = threadIdx.x;
    const int tx = tid & 15, ty = tid >> 4;
    const int row0 = blockIdx.x * 64;
    const int sr = tid >> 4;            // stage row base (0..15), +16 per q
    const int sc = (tid & 15) << 2;     // stage col (float4)
    float acc[4][4] = {};

    int ri[4];
#pragma unroll
    for (int i = 0; i < 4; ++i) ri[i] = min(row0 + ty * 4 + i, N - 1);

    // stage chunk 0 (B0) directly
#pragma unroll
    for (int qq = 0; qq < 4; ++qq)
        *reinterpret_cast<float4*>(&Bs[0][sr + qq * 16][sc]) =
            *reinterpret_cast<const float4*>(B0 + (size_t)(sr + qq * 16) * 64 + sc);
    __syncthreads();

    for (int c = 0; c < 5; ++c) {
        // prefetch next chunk's B into registers (consumed after compute)
        float4 bv[4];
        if (c < 4) {
            const float* Bn = B1 + (size_t)c * 4096;
#pragma unroll
            for (int qq = 0; qq < 4; ++qq)
                bv[qq] = *reinterpret_cast<const float4*>(Bn + (size_t)(sr + qq * 16) * 64 + sc);
        }

        const float* A = (c == 0) ? X : AGG + (c - 1) * 64;
        const int lda = (c == 0) ? 64 : 256;
        const float* pa0 = A + (size_t)ri[0] * lda;
        const float* pa1 = A + (size_t)ri[1] * lda;
        const float* pa2 = A + (size_t)ri[2] * lda;
        const float* pa3 = A + (size_t)ri[3] * lda;
        const int buf = c & 1;
#pragma unroll 4
        for (int k = 0; k < 64; k += 4) {
            float4 a0 = *reinterpret_cast<const float4*>(pa0 + k);
            float4 a1 = *reinterpret_cast<const float4*>(pa1 + k);
            float4 a2 = *reinterpret_cast<const float4*>(pa2 + k);
            float4 a3 = *reinterpret_cast<const float4*>(pa3 + k);
            float4 b0 = *reinterpret_cast<const float4*>(&Bs[buf][k + 0][tx * 4]);
            float4 b1 = *reinterpret_cast<const float4*>(&Bs[buf][k + 1][tx * 4]);
            float4 b2 = *reinterpret_cast<const float4*>(&Bs[buf][k + 2][tx * 4]);
            float4 b3 = *reinterpret_cast<const float4*>(&Bs[buf][k + 3][tx * 4]);
#define DOT4(ai, r) \
            acc[r][0] += ai.x * b0.x + ai.y * b1.x + ai.z * b2.x + ai.w * b3.x; \
            acc[r][1] += ai.x * b0.y + ai.y * b1.y + ai.z * b2.y + ai.w * b3.y; \
            acc[r][2] += ai.x * b0.z + ai.y * b1.z + ai.z * b2.z + ai.w * b3.z; \
            acc[r][3] += ai.x * b0.w + ai.y * b1.w + ai.z * b2.w + ai.w * b3.w;
            DOT4(a0, 0) DOT4(a1, 1) DOT4(a2, 2) DOT4(a3, 3)
#undef DOT4
        }
        if (c < 4) {
            const int nb = (c + 1) & 1;
#pragma unroll
            for (int qq = 0; qq < 4; ++qq)
                *reinterpret_cast<float4*>(&Bs[nb][sr + qq * 16][sc]) = bv[qq];
            __syncthreads();
        }
    }

#pragma unroll
    for (int i = 0; i < 4; ++i) {
        int vr = row0 + ty * 4 + i;
        if (vr >= N) continue;
        float dg = fmaxf((float)(rp2[vr * 4 + 4] - rp2[vr * 4]), 1.f);
        float4 o;
        o.x = fmaxf(acc[i][0] / dg, 0.f);
        o.y = fmaxf(acc[i][1] / dg, 0.f);
        o.z = fmaxf(acc[i][2] / dg, 0.f);
        o.w = fmaxf(acc[i][3] / dg, 0.f);
        *reinterpret_cast<float4*>(OUT + (size_t)vr * 64 + tx * 4) = o;
    }
}

// plain OUT = A @ B (A:[N x 64], B:[64 x 64]) — A from global, B-only LDS
__global__ __launch_bounds__(256, 4) void gemm64(
    const float* __restrict__ A, const float* __restrict__ B,
    float* __restrict__ OUT, int N) {
    __shared__ float Bs[64][68];
    const int tid = threadIdx.x;
    const int tx = tid & 15, ty = tid >> 4;
    const int row0 = blockIdx.x * 64;
    const int sr = tid >> 4;
    const int sc = (tid & 15) << 2;
#pragma unroll
    for (int qq = 0; qq < 4; ++qq)
        *reinterpret_cast<float4*>(&Bs[sr + qq * 16][sc]) =
            *reinterpret_cast<const float4*>(B + (size_t)(sr + qq * 16) * 64 + sc);
    __syncthreads();

    const float* pa[4];
#pragma unroll
    for (int i = 0; i < 4; ++i)
        pa[i] = A + (size_t)min(row0 + ty * 4 + i, N - 1) * 64;

    float acc[4][4] = {};
#pragma unroll 4
    for (int k = 0; k < 64; k += 4) {
        float4 a0 = *reinterpret_cast<const float4*>(pa[0] + k);
        float4 a1 = *reinterpret_cast<const float4*>(pa[1] + k);
        float4 a2 = *reinterpret_cast<const float4*>(pa[2] + k);
        float4 a3 = *reinterpret_cast<const float4*>(pa[3] + k);
        float4 b0 = *reinterpret_cast<const float4*>(&Bs[k + 0][tx * 4]);
        float4 b1 = *reinterpret_cast<const float4*>(&Bs[k + 1][tx * 4]);
        float4 b2 = *reinterpret_cast<const float4*>(&Bs[k + 2][tx * 4]);
        float4 b3 = *reinterpret_cast<const float4*>(&Bs[k + 3][tx * 4]);
#define DOT4(ai, r) \
        acc[r][0] += ai.x * b0.x + ai.y * b1.x + ai.z * b2.x + ai.w * b3.x; \
        acc[r][1] += ai.x * b0.y + ai.y * b1.y + ai.z * b2.y + ai.w * b3.y; \
        acc[r][2] += ai.x * b0.z + ai.y * b1.z + ai.z * b2.z + ai.w * b3.z; \
        acc[r][3] += ai.x * b0.w + ai.y * b1.w + ai.z * b2.w + ai.w * b3.w;
        DOT4(a0, 0) DOT4(a1, 1) DOT4(a2, 2) DOT4(a3, 3)
#undef DOT4
    }
#pragma unroll
    for (int i = 0; i < 4; ++i) {
        int vr = row0 + ty * 4 + i;
        if (vr >= N) continue;
        *reinterpret_cast<float4*>(OUT + (size_t)vr * 64 + tx * 4) =
            make_float4(acc[i][0], acc[i][1], acc[i][2], acc[i][3]);
    }
}

// one block: b2[64][64] = [outW | P2@outW]; b2[4096+j] = alpha2*(pb2@outW)[j]+outb[j]
__global__ __launch_bounds__(256) void prep_b2(
    const float* __restrict__ P2, const float* __restrict__ outW,
    const float* __restrict__ pb2, const float* __restrict__ alphap,
    const float* __restrict__ outb, float* __restrict__ b2) {
    int tid = threadIdx.x;
    int r = tid >> 2;
    int j0 = (tid & 3) * 8;
    float acc[8] = {};
    for (int k = 0; k < 64; ++k) {
        float p = P2[r * 64 + k];
#pragma unroll
        for (int jj = 0; jj < 8; ++jj) acc[jj] += p * outW[k * 32 + j0 + jj];
    }
#pragma unroll
    for (int jj = 0; jj < 8; ++jj) {
        b2[r * 64 + 32 + j0 + jj] = acc[jj];
        b2[r * 64 + j0 + jj] = outW[r * 32 + j0 + jj];
    }
    if (tid < 32) {
        float c = 0.f;
        for (int k = 0; k < 64; ++k) c += pb2[k] * outW[k * 32 + tid];
        b2[4096 + tid] = alphap[0] * c + outb[tid];
    }
}

// g[v] = H[v] + alpha*((sum_e w_e HP[src_e])/deg + pb)
__global__ __launch_bounds__(256) void gather_res(
    const float* __restrict__ HP, const float* __restrict__ H,
    const int* __restrict__ rp2, const int2* __restrict__ pw,
    const float* __restrict__ pb, const float* __restrict__ alphap,
    float* __restrict__ G, int N) {
    int node = blockIdx.x * 4 + (threadIdx.x >> 6);
    if (node >= N) return;
    int lane = threadIdx.x & 63;
    int q = lane >> 4, m = lane & 15;
    int beg = rp2[node * 4], end = rp2[node * 4 + 4];
    float4 acc = make_float4(0.f, 0.f, 0.f, 0.f);
    int i = beg + q;
    for (; i + 4 < end; i += 8) {
        int2 a = pw[i];
        int2 b = pw[i + 4];
        float4 xa = *reinterpret_cast<const float4*>(HP + (size_t)a.x * 64 + m * 4);
        float4 xb = *reinterpret_cast<const float4*>(HP + (size_t)b.x * 64 + m * 4);
        float wa = __int_as_float(a.y), wb = __int_as_float(b.y);
        acc.x += wa * xa.x; acc.y += wa * xa.y; acc.z += wa * xa.z; acc.w += wa * xa.w;
        acc.x += wb * xb.x; acc.y += wb * xb.y; acc.z += wb * xb.z; acc.w += wb * xb.w;
    }
    if (i < end) {
        int2 a = pw[i];
        float4 xa = *reinterpret_cast<const float4*>(HP + (size_t)a.x * 64 + m * 4);
        float wa = __int_as_float(a.y);
        acc.x += wa * xa.x; acc.y += wa * xa.y; acc.z += wa * xa.z; acc.w += wa * xa.w;
    }
#pragma unroll
    for (int off = 16; off < 64; off <<= 1) {
        acc.x += __shfl_xor(acc.x, off);
        acc.y += __shfl_xor(acc.y, off);
        acc.z += __shfl_xor(acc.z, off);
        acc.w += __shfl_xor(acc.w, off);
    }
    if (q == 0) {
        float inv = 1.f / fmaxf((float)(end - beg), 1.f);
        float alpha = alphap[0];
        float4 h = *reinterpret_cast<const float4*>(H + (size_t)node * 64 + m * 4);
        float4 pbv = *reinterpret_cast<const float4*>(pb + m * 4);
        float4 o;
        o.x = h.x + alpha * (acc.x * inv + pbv.x);
        o.y = h.y + alpha * (acc.y * inv + pbv.y);
        o.z = h.z + alpha * (acc.z * inv + pbv.z);
        o.w = h.w + alpha * (acc.w * inv + pbv.w);
        *reinterpret_cast<float4*>(G + (size_t)node * 64 + m * 4) = o;
    }
}

// out[v] = U[v] + alpha*(sum_e w_e T[src_e])/deg + c,  UT[v] = [U(32) | T(32)]
__global__ __launch_bounds__(256) void gather_res_head(
    const float* __restrict__ UT, const int* __restrict__ rp2,
    const int2* __restrict__ pw, const float* __restrict__ b2,
    const float* __restrict__ alphap, float* __restrict__ OUT, int N) {
    int node = blockIdx.x * 4 + (threadIdx.x >> 6);
    if (node >= N) return;
    int lane = threadIdx.x & 63;
    int oct = lane >> 3, m = lane & 7;
    int beg = rp2[node * 4], end = rp2[node * 4 + 4];
    float4 acc = make_float4(0.f, 0.f, 0.f, 0.f);
    for (int i = beg + oct; i < end; i += 8) {
        int2 a = pw[i];
        float4 t = *reinterpret_cast<const float4*>(UT + (size_t)a.x * 64 + 32 + m * 4);
        float w = __int_as_float(a.y);
        acc.x += w * t.x; acc.y += w * t.y; acc.z += w * t.z; acc.w += w * t.w;
    }
#pragma unroll
    for (int off = 8; off < 64; off <<= 1) {
        acc.x += __shfl_xor(acc.x, off);
        acc.y += __shfl_xor(acc.y, off);
        acc.z += __shfl_xor(acc.z, off);
        acc.w += __shfl_xor(acc.w, off);
    }
    if (oct == 0) {
        float s = alphap[0] / fmaxf((float)(end - beg), 1.f);
        float4 u = *reinterpret_cast<const float4*>(UT + (size_t)node * 64 + m * 4);
        float4 cv = *reinterpret_cast<const float4*>(b2 + 4096 + m * 4);
        float4 o;
        o.x = u.x + s * acc.x + cv.x;
        o.y = u.y + s * acc.y + cv.y;
        o.z = u.z + s * acc.z + cv.z;
        o.w = u.w + s * acc.w + cv.w;
        *reinterpret_cast<float4*>(OUT + (size_t)node * 32 + m * 4) = o;
    }
}

extern "C" void kernel_launch(void* const* d_in, const int* in_sizes, int n_in,
                              void* d_out, int out_size, void* d_ws, size_t ws_size,
                              hipStream_t stream) {
    const float* x      = (const float*)d_in[0];
    const int*   ei     = (const int*)d_in[1];
    const int*   et     = (const int*)d_in[2];
    const float* ew     = (const float*)d_in[3];
    const float* W1     = (const float*)d_in[4];
    const float* W01    = (const float*)d_in[5];
    const float* alpha1 = (const float*)d_in[6];
    const float* projW1 = (const float*)d_in[7];
    const float* projb1 = (const float*)d_in[8];
    const float* W2     = (const float*)d_in[9];
    const float* W02    = (const float*)d_in[10];
    const float* alpha2 = (const float*)d_in[11];
    const float* projW2 = (const float*)d_in[12];
    const float* projb2 = (const float*)d_in[13];
    const float* outW   = (const float*)d_in[14];
    const float* outb   = (const float*)d_in[15];
    const int N = in_sizes[0] / 64;
    const int E = in_sizes[2];
    const int M = 4 * N;

    int*   counts4 = (int*)d_ws;
    int*   rp2     = counts4 + M;
    int*   bsum    = rp2 + M + 1;
    int2*  pw      = (int2*)(bsum + 1024);
    float* b2      = (float*)(pw + E);
    float* aggR    = b2 + 4096 + 64;
    float* hbuf    = aggR + (size_t)N * 256;
    float* gbuf    = hbuf + (size_t)N * 64;
    float* hpbuf   = aggR;   // overlay: aggR dead after rgcn_gemm consumes it
    float* utbuf   = aggR;

    const int nb = (M + 1023) / 1024;
    const int gatherBlocks = (N + 3) / 4;
    const int gemmBlocks = (N + 63) / 64;
    const int eBlocks = (E + 255) / 256;

    // ---- CSR build (once per call) ----
    hipMemsetAsync(counts4, 0, (size_t)M * 4, stream);
    hist_dst<<<eBlocks, 256, 0, stream>>>(ei, et, counts4, E);
    scan_block<<<nb, 256, 0, stream>>>(counts4, rp2, bsum, M);
    scan_tops<<<1, 1024, 0, stream>>>(bsum, nb);
    scan_add2<<<(M + 255) / 256, 256, 0, stream>>>(rp2, counts4, bsum, M, E);
    csr_fill<<<eBlocks, 256, 0, stream>>>(ei, et, ew, counts4, pw, E);
    prep_b2<<<1, 256, 0, stream>>>(projW2, outW, projb2, alpha2, outb, b2);

    // ---- layer 1 ----
    gather_rel<<<gatherBlocks, 256, 0, stream>>>(x, rp2, pw, aggR, N);
    rgcn_gemm<<<gemmBlocks, 256, 0, stream>>>(x, aggR, W01, W1, rp2, hbuf, N);
    gemm64<<<gemmBlocks, 256, 0, stream>>>(hbuf, projW1, hpbuf, N);
    gather_res<<<gatherBlocks, 256, 0, stream>>>(hpbuf, hbuf, rp2, pw, projb1, alpha1, gbuf, N);

    // ---- layer 2 ----
    gather_rel<<<gatherBlocks, 256, 0, stream>>>(gbuf, rp2, pw, aggR, N);
    rgcn_gemm<<<gemmBlocks, 256, 0, stream>>>(gbuf, aggR, W02, W2, rp2, hbuf, N);
    gemm64<<<gemmBlocks, 256, 0, stream>>>(hbuf, b2, utbuf, N);
    gather_res_head<<<gatherBlocks, 256, 0, stream>>>(utbuf, rp2, pw, b2, alpha2, (float*)d_out, N);
}

// Round 7
// 511.210 us; speedup vs baseline: 1.7169x; 1.0139x over previous
//
#include <hip/hip_runtime.h>

// ---------------------------------------------------------------------------
// MR_GNN: 2x (RGCN + GroupEnhance) + linear head.
// R6 -> R7: rgcn_gemm was grid-limited (782 blocks = 3/CU, 21% occupancy).
// (a) BM=32 -> 1563 blocks, 4 blocks/CU (LDS-capped), ~16 waves/CU.
// (b) gemm64 fused into the RGCN GEMM epilogue: P staged via the existing
//     B double-buffer prefetch slot, h staged into Bs[0], one extra 64-k
//     GEMM -> HP/UT. Layer 2 skips the h global write entirely.
// (c) HP/UT overlaid on aggR at stride 256 (block clobbers only its own
//     rows) -> no extra workspace, gathers read stride-256 rows.
// ---------------------------------------------------------------------------

__global__ void hist_dst(const int* __restrict__ ei, const int* __restrict__ et,
                         int* __restrict__ counts, int E) {
    int e = blockIdx.x * blockDim.x + threadIdx.x;
    if (e < E) atomicAdd(&counts[ei[E + e] * 4 + et[e]], 1);
}

// block-wise exclusive scan: 256 threads x 4 items = 1024 elements/block
__global__ __launch_bounds__(256) void scan_block(const int* __restrict__ in,
                                                  int* __restrict__ out,
                                                  int* __restrict__ bsum, int M) {
    __shared__ int lds[8];
    int base = blockIdx.x * 1024;
    int tid = threadIdx.x;
    int v[4];
    int s = 0;
#pragma unroll
    for (int j = 0; j < 4; ++j) {
        int i = base + tid * 4 + j;
        v[j] = (i < M) ? in[i] : 0;
        s += v[j];
    }
    int lane = tid & 63;
    int wid = tid >> 6;
    int ws = s;
#pragma unroll
    for (int off = 1; off < 64; off <<= 1) {
        int t = __shfl_up(ws, off);
        if (lane >= off) ws += t;
    }
    if (lane == 63) lds[wid] = ws;
    __syncthreads();
    if (tid == 0) {
        int a = 0;
        for (int w = 0; w < 4; ++w) { int t = lds[w]; lds[w] = a; a += t; }
        lds[4] = a;
    }
    __syncthreads();
    int excl = lds[wid] + ws - s;
#pragma unroll
    for (int j = 0; j < 4; ++j) {
        int i = base + tid * 4 + j;
        if (i < M) out[i] = excl;
        excl += v[j];
    }
    if (tid == 0) bsum[blockIdx.x] = lds[4];
}

__global__ __launch_bounds__(1024) void scan_tops(int* __restrict__ bsum, int nb) {
    __shared__ int lds[1024];
    int tid = threadIdx.x;
    int v = (tid < nb) ? bsum[tid] : 0;
    lds[tid] = v;
    __syncthreads();
    int acc = v;
    for (int off = 1; off < 1024; off <<= 1) {
        int t = (tid >= off) ? lds[tid - off] : 0;
        __syncthreads();
        acc += t;
        lds[tid] = acc;
        __syncthreads();
    }
    if (tid < nb) bsum[tid] = acc - v;  // exclusive
}

__global__ void scan_add2(int* __restrict__ rp, int* __restrict__ next,
                          const int* __restrict__ bsum, int M, int E) {
    int i = blockIdx.x * 256 + threadIdx.x;
    if (i < M) {
        int v = rp[i] + bsum[i >> 10];
        rp[i] = v;
        next[i] = v;
    }
    if (i == 0) rp[M] = E;
}

__global__ void csr_fill(const int* __restrict__ ei, const int* __restrict__ et,
                         const float* __restrict__ ew, int* __restrict__ next,
                         int2* __restrict__ pw, int E) {
    int e = blockIdx.x * 256 + threadIdx.x;
    if (e >= E) return;
    int pos = atomicAdd(&next[ei[E + e] * 4 + et[e]], 1);
    pw[pos] = make_int2(ei[e], __float_as_int(ew[e]));
}

// one wave per node; quad q walks relation-segment q alone
__global__ __launch_bounds__(256) void gather_rel(
    const float* __restrict__ X, const int* __restrict__ rp2,
    const int2* __restrict__ pw, float* __restrict__ aggR, int N) {
    int node = blockIdx.x * 4 + (threadIdx.x >> 6);
    if (node >= N) return;
    int lane = threadIdx.x & 63;
    int q = lane >> 4, m = lane & 15;
    int i = rp2[node * 4 + q], end = rp2[node * 4 + q + 1];
    float4 acc = make_float4(0.f, 0.f, 0.f, 0.f);
    for (; i + 1 < end; i += 2) {
        int2 a = pw[i];
        int2 b = pw[i + 1];
        float4 xa = *reinterpret_cast<const float4*>(X + (size_t)a.x * 64 + m * 4);
        float4 xb = *reinterpret_cast<const float4*>(X + (size_t)b.x * 64 + m * 4);
        float wa = __int_as_float(a.y), wb = __int_as_float(b.y);
        acc.x += wa * xa.x; acc.y += wa * xa.y; acc.z += wa * xa.z; acc.w += wa * xa.w;
        acc.x += wb * xb.x; acc.y += wb * xb.y; acc.z += wb * xb.z; acc.w += wb * xb.w;
    }
    if (i < end) {
        int2 a = pw[i];
        float4 xa = *reinterpret_cast<const float4*>(X + (size_t)a.x * 64 + m * 4);
        float wa = __int_as_float(a.y);
        acc.x += wa * xa.x; acc.y += wa * xa.y; acc.z += wa * xa.z; acc.w += wa * xa.w;
    }
    *reinterpret_cast<float4*>(aggR + (size_t)node * 256 + q * 64 + m * 4) = acc;
}

// ---------------------------------------------------------------------------
// Fused RGCN GEMM + trailing projection:
//   h   = relu((X@B0 + AGG@B1)/deg)          (written iff WRITE_H)
//   OUT2= h @ P                              (stride-256 rows, overlay aggR)
// BM=32, 256 threads, 2x4 micro-tile. A from global (L1/L2), B-only LDS
// double-buffered; P rides the same prefetch slot as chunk 5.
// ---------------------------------------------------------------------------
template <int WRITE_H>
__global__ __launch_bounds__(256, 4) void rgcn_fused(
    const float* __restrict__ X, const float* __restrict__ AGG,
    const float* __restrict__ B0, const float* __restrict__ B1,
    const float* __restrict__ P, const int* __restrict__ rp2,
    float* __restrict__ OUTH, float* __restrict__ OUT2, int N) {
    __shared__ float Bs[2][64][68];
    const int tid = threadIdx.x;
    const int tx = tid & 15, ty = tid >> 4;
    const int row0 = blockIdx.x * 32;
    const int sr = tid >> 4;
    const int sc = (tid & 15) << 2;
    float acc[2][4] = {};

    int ri[2];
#pragma unroll
    for (int i = 0; i < 2; ++i) ri[i] = min(row0 + ty * 2 + i, N - 1);

    // stage chunk 0 (B0)
#pragma unroll
    for (int qq = 0; qq < 4; ++qq)
        *reinterpret_cast<float4*>(&Bs[0][sr + qq * 16][sc]) =
            *reinterpret_cast<const float4*>(B0 + (size_t)(sr + qq * 16) * 64 + sc);
    __syncthreads();

    for (int c = 0; c < 5; ++c) {
        // prefetch next B chunk; for c==4 prefetch P (consumed by epilogue)
        const float* Bn = (c < 4) ? B1 + (size_t)c * 4096 : P;
        float4 bv[4];
#pragma unroll
        for (int qq = 0; qq < 4; ++qq)
            bv[qq] = *reinterpret_cast<const float4*>(Bn + (size_t)(sr + qq * 16) * 64 + sc);

        const float* A = (c == 0) ? X : AGG + (c - 1) * 64;
        const int lda = (c == 0) ? 64 : 256;
        const float* pa0 = A + (size_t)ri[0] * lda;
        const float* pa1 = A + (size_t)ri[1] * lda;
        const int buf = c & 1;
#pragma unroll 4
        for (int k = 0; k < 64; k += 4) {
            float4 a0 = *reinterpret_cast<const float4*>(pa0 + k);
            float4 a1 = *reinterpret_cast<const float4*>(pa1 + k);
            float4 b0 = *reinterpret_cast<const float4*>(&Bs[buf][k + 0][tx * 4]);
            float4 b1 = *reinterpret_cast<const float4*>(&Bs[buf][k + 1][tx * 4]);
            float4 b2 = *reinterpret_cast<const float4*>(&Bs[buf][k + 2][tx * 4]);
            float4 b3 = *reinterpret_cast<const float4*>(&Bs[buf][k + 3][tx * 4]);
#define DOT4(ai, r) \
            acc[r][0] += ai.x * b0.x + ai.y * b1.x + ai.z * b2.x + ai.w * b3.x; \
            acc[r][1] += ai.x * b0.y + ai.y * b1.y + ai.z * b2.y + ai.w * b3.y; \
            acc[r][2] += ai.x * b0.z + ai.y * b1.z + ai.z * b2.z + ai.w * b3.z; \
            acc[r][3] += ai.x * b0.w + ai.y * b1.w + ai.z * b2.w + ai.w * b3.w;
            DOT4(a0, 0) DOT4(a1, 1)
#undef DOT4
        }
        *reinterpret_cast<float4*>(&Bs[buf ^ 1][sr + 0 * 16][sc]) = bv[0];
        *reinterpret_cast<float4*>(&Bs[buf ^ 1][sr + 1 * 16][sc]) = bv[1];
        *reinterpret_cast<float4*>(&Bs[buf ^ 1][sr + 2 * 16][sc]) = bv[2];
        *reinterpret_cast<float4*>(&Bs[buf ^ 1][sr + 3 * 16][sc]) = bv[3];
        __syncthreads();
    }
    // loop ends: Bs[1] holds P; all chunk-4 reads of Bs[0] are done (barrier).

    // epilogue part 1: h = relu(acc/deg); optional global write; stage h->Bs[0]
#pragma unroll
    for (int i = 0; i < 2; ++i) {
        int vr = row0 + ty * 2 + i;
        int cvr = min(vr, N - 1);
        float dg = fmaxf((float)(rp2[cvr * 4 + 4] - rp2[cvr * 4]), 1.f);
        float4 h;
        h.x = fmaxf(acc[i][0] / dg, 0.f);
        h.y = fmaxf(acc[i][1] / dg, 0.f);
        h.z = fmaxf(acc[i][2] / dg, 0.f);
        h.w = fmaxf(acc[i][3] / dg, 0.f);
        if (WRITE_H && vr < N)
            *reinterpret_cast<float4*>(OUTH + (size_t)vr * 64 + tx * 4) = h;
        *reinterpret_cast<float4*>(&Bs[0][ty * 2 + i][tx * 4]) = h;
    }
    __syncthreads();

    // epilogue part 2: OUT2 = h @ P  (h rows in Bs[0][0..31], P in Bs[1])
    float acc2[2][4] = {};
#pragma unroll 4
    for (int k = 0; k < 64; k += 4) {
        float4 a0 = *reinterpret_cast<const float4*>(&Bs[0][ty * 2 + 0][k]);
        float4 a1 = *reinterpret_cast<const float4*>(&Bs[0][ty * 2 + 1][k]);
        float4 b0 = *reinterpret_cast<const float4*>(&Bs[1][k + 0][tx * 4]);
        float4 b1 = *reinterpret_cast<const float4*>(&Bs[1][k + 1][tx * 4]);
        float4 b2 = *reinterpret_cast<const float4*>(&Bs[1][k + 2][tx * 4]);
        float4 b3 = *reinterpret_cast<const float4*>(&Bs[1][k + 3][tx * 4]);
#define DOT4(ai, r) \
        acc2[r][0] += ai.x * b0.x + ai.y * b1.x + ai.z * b2.x + ai.w * b3.x; \
        acc2[r][1] += ai.x * b0.y + ai.y * b1.y + ai.z * b2.y + ai.w * b3.y; \
        acc2[r][2] += ai.x * b0.z + ai.y * b1.z + ai.z * b2.z + ai.w * b3.z; \
        acc2[r][3] += ai.x * b0.w + ai.y * b1.w + ai.z * b2.w + ai.w * b3.w;
        DOT4(a0, 0) DOT4(a1, 1)
#undef DOT4
    }
#pragma unroll
    for (int i = 0; i < 2; ++i) {
        int vr = row0 + ty * 2 + i;
        if (vr >= N) continue;
        *reinterpret_cast<float4*>(OUT2 + (size_t)vr * 256 + tx * 4) =
            make_float4(acc2[i][0], acc2[i][1], acc2[i][2], acc2[i][3]);
    }
}

// one block: b2[64][64] = [outW | P2@outW]; b2[4096+j] = alpha2*(pb2@outW)[j]+outb[j]
__global__ __launch_bounds__(256) void prep_b2(
    const float* __restrict__ P2, const float* __restrict__ outW,
    const float* __restrict__ pb2, const float* __restrict__ alphap,
    const float* __restrict__ outb, float* __restrict__ b2) {
    int tid = threadIdx.x;
    int r = tid >> 2;
    int j0 = (tid & 3) * 8;
    float acc[8] = {};
    for (int k = 0; k < 64; ++k) {
        float p = P2[r * 64 + k];
#pragma unroll
        for (int jj = 0; jj < 8; ++jj) acc[jj] += p * outW[k * 32 + j0 + jj];
    }
#pragma unroll
    for (int jj = 0; jj < 8; ++jj) {
        b2[r * 64 + 32 + j0 + jj] = acc[jj];
        b2[r * 64 + j0 + jj] = outW[r * 32 + j0 + jj];
    }
    if (tid < 32) {
        float c = 0.f;
        for (int k = 0; k < 64; ++k) c += pb2[k] * outW[k * 32 + tid];
        b2[4096 + tid] = alphap[0] * c + outb[tid];
    }
}

// g[v] = H[v] + alpha*((sum_e w_e HP[src_e])/deg + pb); HP rows stride 256
__global__ __launch_bounds__(256) void gather_res(
    const float* __restrict__ HP, const float* __restrict__ H,
    const int* __restrict__ rp2, const int2* __restrict__ pw,
    const float* __restrict__ pb, const float* __restrict__ alphap,
    float* __restrict__ G, int N) {
    int node = blockIdx.x * 4 + (threadIdx.x >> 6);
    if (node >= N) return;
    int lane = threadIdx.x & 63;
    int q = lane >> 4, m = lane & 15;
    int beg = rp2[node * 4], end = rp2[node * 4 + 4];
    float4 acc = make_float4(0.f, 0.f, 0.f, 0.f);
    int i = beg + q;
    for (; i + 4 < end; i += 8) {
        int2 a = pw[i];
        int2 b = pw[i + 4];
        float4 xa = *reinterpret_cast<const float4*>(HP + (size_t)a.x * 256 + m * 4);
        float4 xb = *reinterpret_cast<const float4*>(HP + (size_t)b.x * 256 + m * 4);
        float wa = __int_as_float(a.y), wb = __int_as_float(b.y);
        acc.x += wa * xa.x; acc.y += wa * xa.y; acc.z += wa * xa.z; acc.w += wa * xa.w;
        acc.x += wb * xb.x; acc.y += wb * xb.y; acc.z += wb * xb.z; acc.w += wb * xb.w;
    }
    if (i < end) {
        int2 a = pw[i];
        float4 xa = *reinterpret_cast<const float4*>(HP + (size_t)a.x * 256 + m * 4);
        float wa = __int_as_float(a.y);
        acc.x += wa * xa.x; acc.y += wa * xa.y; acc.z += wa * xa.z; acc.w += wa * xa.w;
    }
#pragma unroll
    for (int off = 16; off < 64; off <<= 1) {
        acc.x += __shfl_xor(acc.x, off);
        acc.y += __shfl_xor(acc.y, off);
        acc.z += __shfl_xor(acc.z, off);
        acc.w += __shfl_xor(acc.w, off);
    }
    if (q == 0) {
        float inv = 1.f / fmaxf((float)(end - beg), 1.f);
        float alpha = alphap[0];
        float4 h = *reinterpret_cast<const float4*>(H + (size_t)node * 64 + m * 4);
        float4 pbv = *reinterpret_cast<const float4*>(pb + m * 4);
        float4 o;
        o.x = h.x + alpha * (acc.x * inv + pbv.x);
        o.y = h.y + alpha * (acc.y * inv + pbv.y);
        o.z = h.z + alpha * (acc.z * inv + pbv.z);
        o.w = h.w + alpha * (acc.w * inv + pbv.w);
        *reinterpret_cast<float4*>(G + (size_t)node * 64 + m * 4) = o;
    }
}

// out[v] = U[v] + alpha*(sum_e w_e T[src_e])/deg + c; UT rows stride 256,
// UT[v] = [U(32) | T(32)] in the row's first 64 floats.
__global__ __launch_bounds__(256) void gather_res_head(
    const float* __restrict__ UT, const int* __restrict__ rp2,
    const int2* __restrict__ pw, const float* __restrict__ b2,
    const float* __restrict__ alphap, float* __restrict__ OUT, int N) {
    int node = blockIdx.x * 4 + (threadIdx.x >> 6);
    if (node >= N) return;
    int lane = threadIdx.x & 63;
    int oct = lane >> 3, m = lane & 7;
    int beg = rp2[node * 4], end = rp2[node * 4 + 4];
    float4 acc = make_float4(0.f, 0.f, 0.f, 0.f);
    for (int i = beg + oct; i < end; i += 8) {
        int2 a = pw[i];
        float4 t = *reinterpret_cast<const float4*>(UT + (size_t)a.x * 256 + 32 + m * 4);
        float w = __int_as_float(a.y);
        acc.x += w * t.x; acc.y += w * t.y; acc.z += w * t.z; acc.w += w * t.w;
    }
#pragma unroll
    for (int off = 8; off < 64; off <<= 1) {
        acc.x += __shfl_xor(acc.x, off);
        acc.y += __shfl_xor(acc.y, off);
        acc.z += __shfl_xor(acc.z, off);
        acc.w += __shfl_xor(acc.w, off);
    }
    if (oct == 0) {
        float s = alphap[0] / fmaxf((float)(end - beg), 1.f);
        float4 u = *reinterpret_cast<const float4*>(UT + (size_t)node * 256 + m * 4);
        float4 cv = *reinterpret_cast<const float4*>(b2 + 4096 + m * 4);
        float4 o;
        o.x = u.x + s * acc.x + cv.x;
        o.y = u.y + s * acc.y + cv.y;
        o.z = u.z + s * acc.z + cv.z;
        o.w = u.w + s * acc.w + cv.w;
        *reinterpret_cast<float4*>(OUT + (size_t)node * 32 + m * 4) = o;
    }
}

extern "C" void kernel_launch(void* const* d_in, const int* in_sizes, int n_in,
                              void* d_out, int out_size, void* d_ws, size_t ws_size,
                              hipStream_t stream) {
    const float* x      = (const float*)d_in[0];
    const int*   ei     = (const int*)d_in[1];
    const int*   et     = (const int*)d_in[2];
    const float* ew     = (const float*)d_in[3];
    const float* W1     = (const float*)d_in[4];
    const float* W01    = (const float*)d_in[5];
    const float* alpha1 = (const float*)d_in[6];
    const float* projW1 = (const float*)d_in[7];
    const float* projb1 = (const float*)d_in[8];
    const float* W2     = (const float*)d_in[9];
    const float* W02    = (const float*)d_in[10];
    const float* alpha2 = (const float*)d_in[11];
    const float* projW2 = (const float*)d_in[12];
    const float* projb2 = (const float*)d_in[13];
    const float* outW   = (const float*)d_in[14];
    const float* outb   = (const float*)d_in[15];
    const int N = in_sizes[0] / 64;
    const int E = in_sizes[2];
    const int M = 4 * N;

    int*   counts4 = (int*)d_ws;
    int*   rp2     = counts4 + M;
    int*   bsum    = rp2 + M + 1;
    int2*  pw      = (int2*)(bsum + 1024);
    float* b2      = (float*)(pw + E);
    float* aggR    = b2 + 4096 + 64;
    float* hbuf    = aggR + (size_t)N * 256;
    float* gbuf    = hbuf + (size_t)N * 64;

    const int nb = (M + 1023) / 1024;
    const int gatherBlocks = (N + 3) / 4;
    const int fusedBlocks = (N + 31) / 32;
    const int eBlocks = (E + 255) / 256;

    // ---- CSR build (once per call) ----
    hipMemsetAsync(counts4, 0, (size_t)M * 4, stream);
    hist_dst<<<eBlocks, 256, 0, stream>>>(ei, et, counts4, E);
    scan_block<<<nb, 256, 0, stream>>>(counts4, rp2, bsum, M);
    scan_tops<<<1, 1024, 0, stream>>>(bsum, nb);
    scan_add2<<<(M + 255) / 256, 256, 0, stream>>>(rp2, counts4, bsum, M, E);
    csr_fill<<<eBlocks, 256, 0, stream>>>(ei, et, ew, counts4, pw, E);
    prep_b2<<<1, 256, 0, stream>>>(projW2, outW, projb2, alpha2, outb, b2);

    // ---- layer 1 ----
    gather_rel<<<gatherBlocks, 256, 0, stream>>>(x, rp2, pw, aggR, N);
    rgcn_fused<1><<<fusedBlocks, 256, 0, stream>>>(x, aggR, W01, W1, projW1, rp2,
                                                   hbuf, aggR, N);       // h + HP(stride256)
    gather_res<<<gatherBlocks, 256, 0, stream>>>(aggR, hbuf, rp2, pw, projb1, alpha1, gbuf, N);

    // ---- layer 2 ----
    gather_rel<<<gatherBlocks, 256, 0, stream>>>(gbuf, rp2, pw, aggR, N);
    rgcn_fused<0><<<fusedBlocks, 256, 0, stream>>>(gbuf, aggR, W02, W2, b2, rp2,
                                                   nullptr, aggR, N);    // UT(stride256)
    gather_res_head<<<gatherBlocks, 256, 0, stream>>>(aggR, rp2, pw, b2, alpha2, (float*)d_out, N);
}